// Round 4
// baseline (132.106 us; speedup 1.0000x reference)
//
#include <hip/hip_runtime.h>
#include <hip/hip_bf16.h>

// Net_27358941675610: the 50-step scan collapses to its fixed point:
//   R   = 0.35*sigmoid((6/7)*(psp^T @ W_h^T + b_h))            [4096,2048]
//   out = 0.35*sigmoid(0.75*(R @ W_o^T + b_o) + 0.125*label)   [4096,512]
// Inputs fp32, output fp32. Internal: bf16 MFMA, fp32 acc.
// R19: gemm1 ported to the 8-phase counted-vmcnt template (T3+T4+T5,
// learn_hip m201 recipe) at 128x256 tile: grid (32,8)=256 -> exactly
// 1 block/CU, 8 waves of 64x64 (2x2 frags of 32x32, R16-proven math),
// 3-deep LDS (144KB), stage tile t+2 during tile t spread over phases
// 0-2, per-tile vmcnt(6) at phase 3 (FIFO drains exactly t+1's loads).
// Per phase: 4 ds_read_b128 + <=2 gld_lds + barrier + lgkmcnt(0) +
// setprio(1) + 4 MFMA + setprio(0) + barrier. The m97-class 2-barrier
// loop plateaued at ~395 TF at this shape (R15/R17/R18 all ~43.5us).
// gemm2 = R18 (64x64, BK=128 two-panel). prep unchanged.

typedef __bf16 bf16_t;
typedef __bf16 bf16x8 __attribute__((ext_vector_type(8)));
typedef __bf16 bf16x4v __attribute__((ext_vector_type(4)));
typedef float f32x4 __attribute__((ext_vector_type(4)));
typedef float f32x16 __attribute__((ext_vector_type(16)));

#define GLD_TO_LDS16(gp, lp)                                            \
  __builtin_amdgcn_global_load_lds(                                     \
      (__attribute__((address_space(1))) void*)(void*)(gp),             \
      (__attribute__((address_space(3))) void*)(lp), 16, 0, 0)

// ---- prep: psp transpose+cvt AND both weight cvts, one kernel ------------
__global__ __launch_bounds__(256) void prep(
    const float* __restrict__ psp, bf16_t* __restrict__ pspT,
    const float4* __restrict__ w1, bf16x4v* __restrict__ o1, int n1,
    const float4* __restrict__ w2, bf16x4v* __restrict__ o2, int n2) {
  __shared__ float tile[64][65];
  const int tid = threadIdx.x;
  const int b = blockIdx.x;
  const int c0 = (b & 63) * 64;   // batch dim
  const int r0 = (b >> 6) * 64;   // in dim
  const int tx = tid & 63;
  const int ty = tid >> 6;
#pragma unroll
  for (int i = 0; i < 16; ++i) {
    const int r = ty + i * 4;
    tile[r][tx] = psp[(size_t)(r0 + r) * 4096 + c0 + tx];
  }
  const int base = b * 768 + tid;
#pragma unroll
  for (int i = 0; i < 3; ++i) {
    const int idx = base + i * 256;
    const float4 v = (idx < n1) ? w1[idx] : w2[idx - n1];
    bf16x4v o;
    o.x = (bf16_t)v.x; o.y = (bf16_t)v.y; o.z = (bf16_t)v.z; o.w = (bf16_t)v.w;
    if (idx < n1) o1[idx] = o;
    else if (idx - n1 < n2) o2[idx - n1] = o;
  }
  __syncthreads();
#pragma unroll
  for (int i = 0; i < 16; ++i) {
    const int r = ty + i * 4;
    pspT[(size_t)(c0 + r) * 1024 + r0 + tx] = (bf16_t)tile[tx][r];
  }
}

// ---- GEMM1: R(bf16) = 0.35*sigmoid(6/7*(A @ Bt^T + bias)) ----------------
// 8-phase counted-vmcnt schedule. mfma_f32_32x32x16_bf16.
// 128x256 tile, 8 waves (2M x 4N) of 64x64, BK=64, 3-deep LDS 144KB,
// grid (32,8)=256 -> 1 block/CU exactly.
__global__ __launch_bounds__(512, 2) void gemm1_nt(
    const bf16_t* __restrict__ A, const bf16_t* __restrict__ Bt,
    const float* __restrict__ bias, bf16_t* __restrict__ C,
    int M, int N, int K) {
  constexpr int BK = 64;
  __shared__ __align__(16) bf16_t sA[3][128 * BK];  // 48 KB
  __shared__ __align__(16) bf16_t sB[3][256 * BK];  // 96 KB

  const int tid = threadIdx.x;
  const int wave = tid >> 6;  // 0..7
  const int lane = tid & 63;
  const int bm = blockIdx.x * 128;
  const int bn = blockIdx.y * 256;
  const int wm = (wave & 1) * 64;   // 2 M-positions
  const int wn = (wave >> 1) * 64;  // 4 N-positions

  f32x16 acc[2][2] = {};

  const int srow8 = lane >> 3;
  const int gseg = (lane & 7) ^ srow8;  // pre-swizzled global k-segment
  // wave stages 16 A-rows (2 glds) and 32 B-rows (4 glds) per K-tile
  const bf16_t* Ag = A + (size_t)(bm + wave * 16 + srow8) * K + gseg * 8;
  const bf16_t* Bg = Bt + (size_t)(bn + wave * 32 + srow8) * K + gseg * 8;
  const int dstA = wave * 1024;  // 16 rows * 64
  const int dstB = wave * 2048;  // 32 rows * 64

  const int col = lane & 31;
  const int g = lane >> 5;
  const int NT = K / BK;  // 16

#define STAGE_A2(bufi, t)                                              \
  {                                                                    \
    bf16_t* d_ = &sA[bufi][dstA];                                      \
    const bf16_t* s_ = Ag + (size_t)(t) * BK;                          \
    GLD_TO_LDS16(s_, d_);                                              \
    GLD_TO_LDS16(s_ + (size_t)8 * K, d_ + 512);                        \
  }
#define STAGE_B01(bufi, t)                                             \
  {                                                                    \
    bf16_t* d_ = &sB[bufi][dstB];                                      \
    const bf16_t* s_ = Bg + (size_t)(t) * BK;                          \
    GLD_TO_LDS16(s_, d_);                                              \
    GLD_TO_LDS16(s_ + (size_t)8 * K, d_ + 512);                        \
  }
#define STAGE_B23(bufi, t)                                             \
  {                                                                    \
    bf16_t* d_ = &sB[bufi][dstB + 1024];                               \
    const bf16_t* s_ = Bg + (size_t)(t) * BK + (size_t)16 * K;         \
    GLD_TO_LDS16(s_, d_);                                              \
    GLD_TO_LDS16(s_ + (size_t)8 * K, d_ + 512);                        \
  }
#define PH_READ(ks)                                                    \
  {                                                                    \
    const int q = (ks) * 2 + g;                                        \
    _Pragma("unroll") for (int i = 0; i < 2; ++i) {                    \
      const int rr = wm + i * 32 + col;                                \
      av[i] = *(const bf16x8*)(a_ + rr * BK + ((q ^ (rr & 7)) * 8));   \
    }                                                                  \
    _Pragma("unroll") for (int j = 0; j < 2; ++j) {                    \
      const int rr = wn + j * 32 + col;                                \
      bv[j] = *(const bf16x8*)(b_ + rr * BK + ((q ^ (rr & 7)) * 8));   \
    }                                                                  \
  }
#define PH_MFMA()                                                      \
  __builtin_amdgcn_s_setprio(1);                                       \
  _Pragma("unroll") for (int i = 0; i < 2; ++i)                        \
      _Pragma("unroll") for (int j = 0; j < 2; ++j)                    \
          acc[i][j] = __builtin_amdgcn_mfma_f32_32x32x16_bf16(         \
              av[i], bv[j], acc[i][j], 0, 0, 0);                       \
  __builtin_amdgcn_s_setprio(0);
#define SYNC_PRE()                                                     \
  __builtin_amdgcn_sched_barrier(0);                                   \
  __builtin_amdgcn_s_barrier();                                        \
  asm volatile("s_waitcnt lgkmcnt(0)" ::: "memory");                   \
  __builtin_amdgcn_sched_barrier(0);
#define SYNC_POST()                                                    \
  __builtin_amdgcn_sched_barrier(0);                                   \
  __builtin_amdgcn_s_barrier();                                        \
  __builtin_amdgcn_sched_barrier(0);

  // prologue: stage tiles 0 and 1 (12 loads); vmcnt(6) -> tile 0 landed.
  STAGE_A2(0, 0); STAGE_B01(0, 0); STAGE_B23(0, 0);
  STAGE_A2(1, 1); STAGE_B01(1, 1); STAGE_B23(1, 1);
  asm volatile("s_waitcnt vmcnt(6)" ::: "memory");
  __builtin_amdgcn_sched_barrier(0);
  __builtin_amdgcn_s_barrier();
  __builtin_amdgcn_sched_barrier(0);

  int cur = 0;
  for (int t = 0; t < NT; ++t) {
    const bf16_t* a_ = sA[cur];
    const bf16_t* b_ = sB[cur];
    const int nxt = (cur >= 1) ? cur - 1 : cur + 2;  // (t+2)%3
    const bool st = (t + 2) < NT;
    bf16x8 av[2], bv[2];

    // phase 0
    PH_READ(0);
    if (st) STAGE_A2(nxt, t + 2);
    SYNC_PRE(); PH_MFMA(); SYNC_POST();
    // phase 1
    PH_READ(1);
    if (st) STAGE_B01(nxt, t + 2);
    SYNC_PRE(); PH_MFMA(); SYNC_POST();
    // phase 2
    PH_READ(2);
    if (st) STAGE_B23(nxt, t + 2);
    SYNC_PRE(); PH_MFMA(); SYNC_POST();
    // phase 3: per-tile counted wait. FIFO: oldest 6 = tile t+1's loads.
    PH_READ(3);
    if (t + 1 < NT) {
      if (t + 2 < NT)
        asm volatile("s_waitcnt vmcnt(6)" ::: "memory");
      else
        asm volatile("s_waitcnt vmcnt(0)" ::: "memory");
    }
    SYNC_PRE(); PH_MFMA(); SYNC_POST();

    cur = (cur + 1 == 3) ? 0 : cur + 1;
  }
#undef STAGE_A2
#undef STAGE_B01
#undef STAGE_B23
#undef PH_READ
#undef PH_MFMA
#undef SYNC_PRE
#undef SYNC_POST

  // epilogue: col = lane&31, row = (r&3) + 8*(r>>2) + 4*(lane>>5) [m74/m101]
  const int rbase = 4 * g;
#pragma unroll
  for (int j = 0; j < 2; ++j) {
    const int gn = bn + wn + j * 32 + col;
    const float bj = bias[gn];
#pragma unroll
    for (int i = 0; i < 2; ++i) {
#pragma unroll
      for (int r = 0; r < 16; ++r) {
        const int gm = bm + wm + i * 32 + (r & 3) + 8 * (r >> 2) + rbase;
        const float z = 0.8571428571428571f * (acc[i][j][r] + bj);
        C[(size_t)gm * N + gn] = (bf16_t)(0.35f / (1.0f + __expf(-z)));
      }
    }
  }
}

// ---- GEMM2: out(fp32) = 0.35*sigmoid(0.75*(R @ Wo^T + b_o) + 0.125*lbl) --
// R18: 64x64 tile, 4 waves of 32x32 (2x2 frags of 16x16), BK=128 as two
// proven BK=64 panels. 16 epochs, 16 MFMA/epoch/wave, grid (64,8)=512.
__global__ __launch_bounds__(256, 4) void gemm2_nt(
    const bf16_t* __restrict__ A, const bf16_t* __restrict__ Bt,
    const float* __restrict__ bias, const float* __restrict__ lbl,
    float* __restrict__ out, int M, int N, int K) {
  __shared__ __align__(16) bf16_t sA[2][64 * 64];  // 16 KB (2 K-panels)
  __shared__ __align__(16) bf16_t sB[2][64 * 64];  // 16 KB

  const int tid = threadIdx.x;
  const int wave = tid >> 6;
  const int lane = tid & 63;
  const int bm = blockIdx.x * 64;
  const int bn = blockIdx.y * 64;
  const int wm = (wave & 1) * 32;
  const int wn = (wave >> 1) * 32;

  f32x4 acc[2][2] = {};

  const int srow8 = lane >> 3;
  const int gseg = (lane & 7) ^ srow8;  // pre-swizzled global k-segment
  const bf16_t* Ag = A + (size_t)(bm + wave * 16 + srow8) * K + gseg * 8;
  const bf16_t* Bg = Bt + (size_t)(bn + wave * 16 + srow8) * K + gseg * 8;
  const int dst = wave * 1024;  // 16 rows * 64 elems per wave, per panel

  const int fr = lane & 15;
  const int qh = lane >> 4;

  for (int k0 = 0; k0 < K; k0 += 128) {
#pragma unroll
    for (int p = 0; p < 2; ++p) {
#pragma unroll
      for (int c = 0; c < 2; ++c) {
        GLD_TO_LDS16(Ag + k0 + p * 64 + (size_t)(c * 8) * K,
                     sA[p] + dst + c * 512);
        GLD_TO_LDS16(Bg + k0 + p * 64 + (size_t)(c * 8) * K,
                     sB[p] + dst + c * 512);
      }
    }
    __syncthreads();

#pragma unroll
    for (int ks = 0; ks < 4; ++ks) {
      const int q = ks * 4 + qh;   // granule 0..15 across BK=128
      const int pnl = q >> 3;      // panel (wave-uniform per ks)
      const int q2 = q & 7;        // granule within panel
      bf16x8 av[2], bv[2];
#pragma unroll
      for (int i = 0; i < 2; ++i) {
        const int ra = wm + i * 16 + fr;
        av[i] = *(const bf16x8*)(sA[pnl] + ra * 64 + ((q2 ^ (ra & 7)) * 8));
      }
#pragma unroll
      for (int j = 0; j < 2; ++j) {
        const int rb = wn + j * 16 + fr;
        bv[j] = *(const bf16x8*)(sB[pnl] + rb * 64 + ((q2 ^ (rb & 7)) * 8));
      }
#pragma unroll
      for (int i = 0; i < 2; ++i)
#pragma unroll
        for (int j = 0; j < 2; ++j)
          acc[i][j] = __builtin_amdgcn_mfma_f32_16x16x32_bf16(
              av[i], bv[j], acc[i][j], 0, 0, 0);
    }
    __syncthreads();
  }

  // epilogue: col = lane&15, row = (lane>>4)*4 + reg [m89/m91]
  const int cm0 = qh * 4;
#pragma unroll
  for (int j = 0; j < 2; ++j) {
    const int gn = bn + wn + j * 16 + fr;
    const float bj = bias[gn];
#pragma unroll
    for (int i = 0; i < 2; ++i) {
#pragma unroll
      for (int r = 0; r < 4; ++r) {
        const int gm = bm + wm + i * 16 + cm0 + r;
        const float z =
            0.75f * (acc[i][j][r] + bj) + 0.125f * lbl[(size_t)gm * N + gn];
        out[(size_t)gm * N + gn] = 0.35f / (1.0f + __expf(-z));
      }
    }
  }
}

extern "C" void kernel_launch(void* const* d_in, const int* in_sizes, int n_in,
                              void* d_out, int out_size, void* d_ws, size_t ws_size,
                              hipStream_t stream) {
  constexpr int IN = 1024, HID = 2048, OUT = 512, B = 4096;
  const float* psp = (const float*)d_in[0];   // [IN, B]
  const float* lbl = (const float*)d_in[1];   // [B, OUT]
  const float* W_h = (const float*)d_in[2];   // [HID, IN]
  const float* b_h = (const float*)d_in[3];   // [HID]
  const float* W_o = (const float*)d_in[4];   // [OUT, HID]
  const float* b_o = (const float*)d_in[5];   // [OUT]
  float* out = (float*)d_out;                 // [B, OUT] fp32

  bf16_t* Whb = (bf16_t*)d_ws;                 // [HID, IN]  4 MB
  bf16_t* Wob = Whb + (size_t)HID * IN;        // [OUT, HID] 2 MB
  bf16_t* pspT = Wob + (size_t)OUT * HID;      // [B, IN]    8 MB
  bf16_t* Rm = pspT + (size_t)B * IN;          // [B, HID]  16 MB

  prep<<<1024, 256, 0, stream>>>(
      psp, pspT, (const float4*)W_h, (bf16x4v*)Whb, HID * IN / 4,
      (const float4*)W_o, (bf16x4v*)Wob, OUT * HID / 4);
  gemm1_nt<<<dim3(B / 128, HID / 256), 512, 0, stream>>>(
      pspT, Whb, b_h, Rm, B, HID, IN);
  gemm2_nt<<<dim3(B / 64, OUT / 64), 256, 0, stream>>>(
      Rm, Wob, b_o, lbl, out, B, OUT, HID);
}

// Round 5
// 129.027 us; speedup vs baseline: 1.0239x; 1.0239x over previous
//
#include <hip/hip_runtime.h>
#include <hip/hip_bf16.h>

// Net_27358941675610: the 50-step scan collapses to its fixed point:
//   R   = 0.35*sigmoid((6/7)*(psp^T @ W_h^T + b_h))            [4096,2048]
//   out = 0.35*sigmoid(0.75*(R @ W_o^T + b_o) + 0.125*label)   [4096,512]
// Inputs fp32, output fp32. Internal: bf16 MFMA, fp32 acc.
// R20: gemm1 = m201-faithful phase density. R19 failed because phases held
// only 4 MFMA (2x2 of 32x32) per barrier-pair; m201's lever is 16 MFMA
// (4x4 of 16x16) per barrier-pair. BM=128 BN=256, 8 waves (2Mx4N), wave
// tile 64x64 = 4x4 frags of mfma_16x16x32 (R18-proven fragment math),
// BK=64, 2 phases/tile, 3-deep LDS 144KB, vmcnt(6) once per tile after
// phase-1 MFMA (never 0 mid-loop). grid (32,8)=256 -> 1 blk/CU.
// gemm2 = R18 (64x64, BK=128 two-panel). prep unchanged.

typedef __bf16 bf16_t;
typedef __bf16 bf16x8 __attribute__((ext_vector_type(8)));
typedef __bf16 bf16x4v __attribute__((ext_vector_type(4)));
typedef float f32x4 __attribute__((ext_vector_type(4)));
typedef float f32x16 __attribute__((ext_vector_type(16)));

#define GLD_TO_LDS16(gp, lp)                                            \
  __builtin_amdgcn_global_load_lds(                                     \
      (__attribute__((address_space(1))) void*)(void*)(gp),             \
      (__attribute__((address_space(3))) void*)(lp), 16, 0, 0)

// ---- prep: psp transpose+cvt AND both weight cvts, one kernel ------------
__global__ __launch_bounds__(256) void prep(
    const float* __restrict__ psp, bf16_t* __restrict__ pspT,
    const float4* __restrict__ w1, bf16x4v* __restrict__ o1, int n1,
    const float4* __restrict__ w2, bf16x4v* __restrict__ o2, int n2) {
  __shared__ float tile[64][65];
  const int tid = threadIdx.x;
  const int b = blockIdx.x;
  const int c0 = (b & 63) * 64;   // batch dim
  const int r0 = (b >> 6) * 64;   // in dim
  const int tx = tid & 63;
  const int ty = tid >> 6;
#pragma unroll
  for (int i = 0; i < 16; ++i) {
    const int r = ty + i * 4;
    tile[r][tx] = psp[(size_t)(r0 + r) * 4096 + c0 + tx];
  }
  const int base = b * 768 + tid;
#pragma unroll
  for (int i = 0; i < 3; ++i) {
    const int idx = base + i * 256;
    const float4 v = (idx < n1) ? w1[idx] : w2[idx - n1];
    bf16x4v o;
    o.x = (bf16_t)v.x; o.y = (bf16_t)v.y; o.z = (bf16_t)v.z; o.w = (bf16_t)v.w;
    if (idx < n1) o1[idx] = o;
    else if (idx - n1 < n2) o2[idx - n1] = o;
  }
  __syncthreads();
#pragma unroll
  for (int i = 0; i < 16; ++i) {
    const int r = ty + i * 4;
    pspT[(size_t)(c0 + r) * 1024 + r0 + tx] = (bf16_t)tile[tx][r];
  }
}

// ---- GEMM1: R(bf16) = 0.35*sigmoid(6/7*(A @ Bt^T + bias)) ----------------
// m201-density schedule. mfma_f32_16x16x32_bf16, 4x4 frags per wave.
// 128x256 tile, 8 waves (2M x 4N) of 64x64, BK=64, 3-deep LDS 144KB,
// grid (32,8)=256 -> 1 block/CU. 2 phases/tile, 16 MFMA per phase.
__global__ __launch_bounds__(512, 2) void gemm1_nt(
    const bf16_t* __restrict__ A, const bf16_t* __restrict__ Bt,
    const float* __restrict__ bias, bf16_t* __restrict__ C,
    int M, int N, int K) {
  constexpr int BK = 64;
  __shared__ __align__(16) bf16_t sA[3][128 * BK];  // 48 KB
  __shared__ __align__(16) bf16_t sB[3][256 * BK];  // 96 KB

  const int tid = threadIdx.x;
  const int wave = tid >> 6;  // 0..7
  const int lane = tid & 63;
  const int bm = blockIdx.x * 128;
  const int bn = blockIdx.y * 256;
  const int wm = (wave & 1) * 64;   // 2 M-positions
  const int wn = (wave >> 1) * 64;  // 4 N-positions

  f32x4 acc[4][4] = {};

  const int srow8 = lane >> 3;
  const int gseg = (lane & 7) ^ srow8;  // pre-swizzled global k-segment
  // wave stages 16 A-rows (2 glds) and 32 B-rows (4 glds) per K-tile
  const bf16_t* Ag = A + (size_t)(bm + wave * 16 + srow8) * K + gseg * 8;
  const bf16_t* Bg = Bt + (size_t)(bn + wave * 32 + srow8) * K + gseg * 8;
  const int dstA = wave * 1024;  // 16 rows * 64
  const int dstB = wave * 2048;  // 32 rows * 64

  const int fr = lane & 15;
  const int qh = lane >> 4;
  const int NT = K / BK;  // 16

#define STAGE_A2(bufi, t)                                              \
  {                                                                    \
    bf16_t* d_ = &sA[bufi][dstA];                                      \
    const bf16_t* s_ = Ag + (size_t)(t) * BK;                          \
    GLD_TO_LDS16(s_, d_);                                              \
    GLD_TO_LDS16(s_ + (size_t)8 * K, d_ + 512);                        \
  }
#define STAGE_B01(bufi, t)                                             \
  {                                                                    \
    bf16_t* d_ = &sB[bufi][dstB];                                      \
    const bf16_t* s_ = Bg + (size_t)(t) * BK;                          \
    GLD_TO_LDS16(s_, d_);                                              \
    GLD_TO_LDS16(s_ + (size_t)8 * K, d_ + 512);                        \
  }
#define STAGE_B23(bufi, t)                                             \
  {                                                                    \
    bf16_t* d_ = &sB[bufi][dstB + 1024];                               \
    const bf16_t* s_ = Bg + (size_t)(t) * BK + (size_t)16 * K;         \
    GLD_TO_LDS16(s_, d_);                                              \
    GLD_TO_LDS16(s_ + (size_t)8 * K, d_ + 512);                        \
  }
#define PH_READ(ph)                                                    \
  {                                                                    \
    const int q = (ph) * 4 + qh;                                       \
    _Pragma("unroll") for (int i = 0; i < 4; ++i) {                    \
      const int ra = wm + i * 16 + fr;                                 \
      av[i] = *(const bf16x8*)(a_ + ra * BK + ((q ^ (ra & 7)) * 8));   \
    }                                                                  \
    _Pragma("unroll") for (int j = 0; j < 4; ++j) {                    \
      const int rb = wn + j * 16 + fr;                                 \
      bv[j] = *(const bf16x8*)(b_ + rb * BK + ((q ^ (rb & 7)) * 8));   \
    }                                                                  \
  }
#define PH_MFMA()                                                      \
  __builtin_amdgcn_s_setprio(1);                                       \
  _Pragma("unroll") for (int i = 0; i < 4; ++i)                        \
      _Pragma("unroll") for (int j = 0; j < 4; ++j)                    \
          acc[i][j] = __builtin_amdgcn_mfma_f32_16x16x32_bf16(         \
              av[i], bv[j], acc[i][j], 0, 0, 0);                       \
  __builtin_amdgcn_s_setprio(0);
#define SYNC_PRE()                                                     \
  __builtin_amdgcn_sched_barrier(0);                                   \
  __builtin_amdgcn_s_barrier();                                        \
  asm volatile("s_waitcnt lgkmcnt(0)" ::: "memory");                   \
  __builtin_amdgcn_sched_barrier(0);
#define SYNC_POST()                                                    \
  __builtin_amdgcn_sched_barrier(0);                                   \
  __builtin_amdgcn_s_barrier();                                        \
  __builtin_amdgcn_sched_barrier(0);

  // prologue: stage tiles 0 and 1 (12 loads); vmcnt(6) -> tile 0 landed.
  STAGE_A2(0, 0); STAGE_B01(0, 0); STAGE_B23(0, 0);
  STAGE_A2(1, 1); STAGE_B01(1, 1); STAGE_B23(1, 1);
  asm volatile("s_waitcnt vmcnt(6)" ::: "memory");
  __builtin_amdgcn_sched_barrier(0);
  __builtin_amdgcn_s_barrier();
  __builtin_amdgcn_sched_barrier(0);

  int cur = 0;
  for (int t = 0; t < NT; ++t) {
    const bf16_t* a_ = sA[cur];
    const bf16_t* b_ = sB[cur];
    const int nxt = (cur >= 1) ? cur - 1 : 2;  // (t+2)%3
    const bool st = (t + 2) < NT;
    bf16x8 av[4], bv[4];

    // phase 0: k 0..31 of this tile; issue 4 of next-next tile's loads
    PH_READ(0);
    if (st) { STAGE_A2(nxt, t + 2); STAGE_B01(nxt, t + 2); }
    SYNC_PRE(); PH_MFMA(); SYNC_POST();

    // phase 1: k 32..63; issue remaining 2 loads; per-tile counted wait
    PH_READ(1);
    if (st) STAGE_B23(nxt, t + 2);
    SYNC_PRE(); PH_MFMA();
    if (t + 1 < NT) {
      if (st)  // steady: 12 in flight, drain oldest 6 = tile t+1's
        asm volatile("s_waitcnt vmcnt(6)" ::: "memory");
      else     // tail: only t+1's 6 remain
        asm volatile("s_waitcnt vmcnt(0)" ::: "memory");
    }
    SYNC_POST();

    cur = (cur + 1 == 3) ? 0 : cur + 1;
  }
#undef STAGE_A2
#undef STAGE_B01
#undef STAGE_B23
#undef PH_READ
#undef PH_MFMA
#undef SYNC_PRE
#undef SYNC_POST

  // epilogue: col = lane&15, row = (lane>>4)*4 + reg [m89/m91]
  const int cm0 = qh * 4;
#pragma unroll
  for (int j = 0; j < 4; ++j) {
    const int gn = bn + wn + j * 16 + fr;
    const float bj = bias[gn];
#pragma unroll
    for (int i = 0; i < 4; ++i) {
#pragma unroll
      for (int r = 0; r < 4; ++r) {
        const int gm = bm + wm + i * 16 + cm0 + r;
        const float z = 0.8571428571428571f * (acc[i][j][r] + bj);
        C[(size_t)gm * N + gn] = (bf16_t)(0.35f / (1.0f + __expf(-z)));
      }
    }
  }
}

// ---- GEMM2: out(fp32) = 0.35*sigmoid(0.75*(R @ Wo^T + b_o) + 0.125*lbl) --
// R18: 64x64 tile, 4 waves of 32x32 (2x2 frags of 16x16), BK=128 as two
// proven BK=64 panels. 16 epochs, 16 MFMA/epoch/wave, grid (64,8)=512.
__global__ __launch_bounds__(256, 4) void gemm2_nt(
    const bf16_t* __restrict__ A, const bf16_t* __restrict__ Bt,
    const float* __restrict__ bias, const float* __restrict__ lbl,
    float* __restrict__ out, int M, int N, int K) {
  __shared__ __align__(16) bf16_t sA[2][64 * 64];  // 16 KB (2 K-panels)
  __shared__ __align__(16) bf16_t sB[2][64 * 64];  // 16 KB

  const int tid = threadIdx.x;
  const int wave = tid >> 6;
  const int lane = tid & 63;
  const int bm = blockIdx.x * 64;
  const int bn = blockIdx.y * 64;
  const int wm = (wave & 1) * 32;
  const int wn = (wave >> 1) * 32;

  f32x4 acc[2][2] = {};

  const int srow8 = lane >> 3;
  const int gseg = (lane & 7) ^ srow8;  // pre-swizzled global k-segment
  const bf16_t* Ag = A + (size_t)(bm + wave * 16 + srow8) * K + gseg * 8;
  const bf16_t* Bg = Bt + (size_t)(bn + wave * 16 + srow8) * K + gseg * 8;
  const int dst = wave * 1024;  // 16 rows * 64 elems per wave, per panel

  const int fr = lane & 15;
  const int qh = lane >> 4;

  for (int k0 = 0; k0 < K; k0 += 128) {
#pragma unroll
    for (int p = 0; p < 2; ++p) {
#pragma unroll
      for (int c = 0; c < 2; ++c) {
        GLD_TO_LDS16(Ag + k0 + p * 64 + (size_t)(c * 8) * K,
                     sA[p] + dst + c * 512);
        GLD_TO_LDS16(Bg + k0 + p * 64 + (size_t)(c * 8) * K,
                     sB[p] + dst + c * 512);
      }
    }
    __syncthreads();

#pragma unroll
    for (int ks = 0; ks < 4; ++ks) {
      const int q = ks * 4 + qh;   // granule 0..15 across BK=128
      const int pnl = q >> 3;      // panel (wave-uniform per ks)
      const int q2 = q & 7;        // granule within panel
      bf16x8 av[2], bv[2];
#pragma unroll
      for (int i = 0; i < 2; ++i) {
        const int ra = wm + i * 16 + fr;
        av[i] = *(const bf16x8*)(sA[pnl] + ra * 64 + ((q2 ^ (ra & 7)) * 8));
      }
#pragma unroll
      for (int j = 0; j < 2; ++j) {
        const int rb = wn + j * 16 + fr;
        bv[j] = *(const bf16x8*)(sB[pnl] + rb * 64 + ((q2 ^ (rb & 7)) * 8));
      }
#pragma unroll
      for (int i = 0; i < 2; ++i)
#pragma unroll
        for (int j = 0; j < 2; ++j)
          acc[i][j] = __builtin_amdgcn_mfma_f32_16x16x32_bf16(
              av[i], bv[j], acc[i][j], 0, 0, 0);
    }
    __syncthreads();
  }

  // epilogue: col = lane&15, row = (lane>>4)*4 + reg [m89/m91]
  const int cm0 = qh * 4;
#pragma unroll
  for (int j = 0; j < 2; ++j) {
    const int gn = bn + wn + j * 16 + fr;
    const float bj = bias[gn];
#pragma unroll
    for (int i = 0; i < 2; ++i) {
#pragma unroll
      for (int r = 0; r < 4; ++r) {
        const int gm = bm + wm + i * 16 + cm0 + r;
        const float z =
            0.75f * (acc[i][j][r] + bj) + 0.125f * lbl[(size_t)gm * N + gn];
        out[(size_t)gm * N + gn] = 0.35f / (1.0f + __expf(-z));
      }
    }
  }
}

extern "C" void kernel_launch(void* const* d_in, const int* in_sizes, int n_in,
                              void* d_out, int out_size, void* d_ws, size_t ws_size,
                              hipStream_t stream) {
  constexpr int IN = 1024, HID = 2048, OUT = 512, B = 4096;
  const float* psp = (const float*)d_in[0];   // [IN, B]
  const float* lbl = (const float*)d_in[1];   // [B, OUT]
  const float* W_h = (const float*)d_in[2];   // [HID, IN]
  const float* b_h = (const float*)d_in[3];   // [HID]
  const float* W_o = (const float*)d_in[4];   // [OUT, HID]
  const float* b_o = (const float*)d_in[5];   // [OUT]
  float* out = (float*)d_out;                 // [B, OUT] fp32

  bf16_t* Whb = (bf16_t*)d_ws;                 // [HID, IN]  4 MB
  bf16_t* Wob = Whb + (size_t)HID * IN;        // [OUT, HID] 2 MB
  bf16_t* pspT = Wob + (size_t)OUT * HID;      // [B, IN]    8 MB
  bf16_t* Rm = pspT + (size_t)B * IN;          // [B, HID]  16 MB

  prep<<<1024, 256, 0, stream>>>(
      psp, pspT, (const float4*)W_h, (bf16x4v*)Whb, HID * IN / 4,
      (const float4*)W_o, (bf16x4v*)Wob, OUT * HID / 4);
  gemm1_nt<<<dim3(B / 128, HID / 256), 512, 0, stream>>>(
      pspT, Whb, b_h, Rm, B, HID, IN);
  gemm2_nt<<<dim3(B / 64, OUT / 64), 256, 0, stream>>>(
      Rm, Wob, b_o, lbl, out, B, OUT, HID);
}